// Round 3
// baseline (897.346 us; speedup 1.0000x reference)
//
#include <hip/hip_runtime.h>
#include <hip/hip_bf16.h>

#define N_B 1024
#define N_ITEMS 100000
#define N_CLUSTERS 10
#define N_D 64

// ---------------------------------------------------------------------------
// Kernel 1: S1[c][d] = sum_{i: cluster[i]==c} W1[i][d]; counts[c].
// Register accumulators per cluster (predicated selects), lane = d column,
// item index wave-uniform -> cl via scalar load, W1 row coalesced.
// ---------------------------------------------------------------------------
__global__ __launch_bounds__(256) void k1_segsum(
    const int* __restrict__ cl, const float* __restrict__ W1,
    float* __restrict__ S1g, float* __restrict__ cntg) {
  __shared__ float s1[4][N_CLUSTERS][N_D];   // 10 KB
  __shared__ float scnt[4][N_CLUSTERS];
  int t = threadIdx.x;
  int wave = t >> 6, lane = t & 63;

  float a[N_CLUSTERS];
  float cn[N_CLUSTERS];
#pragma unroll
  for (int k = 0; k < N_CLUSTERS; ++k) { a[k] = 0.f; cn[k] = 0.f; }

  int gw = blockIdx.x * 4 + wave;
  int nw = gridDim.x * 4;
#pragma unroll 4
  for (int i = gw; i < N_ITEMS; i += nw) {
    int c = cl[i];                              // wave-uniform -> s_load
    float w = W1[(size_t)i * N_D + lane];       // coalesced 256B/row
#pragma unroll
    for (int k = 0; k < N_CLUSTERS; ++k) {
      bool m = (c == k);
      a[k] += m ? w : 0.f;
      cn[k] += m ? 1.f : 0.f;
    }
  }

#pragma unroll
  for (int k = 0; k < N_CLUSTERS; ++k) s1[wave][k][lane] = a[k];
  if (lane == 0) {
#pragma unroll
    for (int k = 0; k < N_CLUSTERS; ++k) scnt[wave][k] = cn[k];
  }
  __syncthreads();

  const float* fs1 = (const float*)s1;
  for (int i = t; i < N_CLUSTERS * N_D; i += 256) {
    float v = fs1[i] + fs1[640 + i] + fs1[1280 + i] + fs1[1920 + i];
    atomicAdd(&S1g[i], v);
  }
  if (t < N_CLUSTERS) {
    float v = scnt[0][t] + scnt[1][t] + scnt[2][t] + scnt[3][t];
    atomicAdd(&cntg[t], v);
  }
}

// ---------------------------------------------------------------------------
// Kernel 2: hT[d][row] = sum_c input[row][c] * S1[c][d]   (64 x 1024,
// transposed so k3's per-d row-slice is contiguous -> s_load_dwordx16).
// ---------------------------------------------------------------------------
__global__ __launch_bounds__(256) void k2_h(
    const float* __restrict__ inp, const float* __restrict__ S1g,
    float* __restrict__ hT) {
  int idx = blockIdx.x * 256 + threadIdx.x;    // < 65536 exactly
  int d = idx >> 10, row = idx & 1023;
  float acc = 0.f;
#pragma unroll
  for (int c = 0; c < N_CLUSTERS; ++c)
    acc += inp[row * N_CLUSTERS + c] * S1g[c * N_D + d];  // S1 wave-uniform
  hT[idx] = acc;                               // coalesced
}

// ---------------------------------------------------------------------------
// Kernel 3 (hot): thread owns 1 item; acc[32] rows; w[64] = full W2 column
// preloaded upfront (64 independent coalesced loads -> one vmcnt drain).
// Inner loop has ZERO VMEM: per d, a wave-uniform contiguous 128B slice
// hT[d][r0..r0+31] (2x s_load_dwordx16, scalar pipe) + 32 v_fmac with SGPR
// broadcast operand. Register budget: acc[32]+w[64] ~ 110 VGPR -> no loop
// interchange / no spill (R2 failure mode).
// ---------------------------------------------------------------------------
#define ROWS 32
#define REP 4
__global__ __launch_bounds__(256) void k3_main(
    const float* __restrict__ W2, const float* __restrict__ hT,
    const int* __restrict__ cl, float* __restrict__ bucketg) {
  __shared__ float bkt[4][ROWS][N_CLUSTERS * REP];   // 20 KB
  int t = threadIdx.x;
  int wave = t >> 6, lane = t & 63;
  int r0 = blockIdx.x * ROWS;                  // 0..992
  int j = blockIdx.y * 256 + t;
  bool valid = (j < N_ITEMS);
  int jc = valid ? j : (N_ITEMS - 1);          // clamp: loads stay in-bounds

  float* fb = (float*)bkt;
  for (int i = t; i < 4 * ROWS * N_CLUSTERS * REP; i += 256) fb[i] = 0.f;
  __syncthreads();

  // Full W2 column -> 64 VGPRs, all loads independent & coalesced (256B/instr)
  const float* __restrict__ w2col = W2 + jc;
  float w[N_D];
#pragma unroll
  for (int k = 0; k < N_D; ++k) w[k] = w2col[(size_t)k * N_ITEMS];

  float acc[ROWS];
#pragma unroll
  for (int r = 0; r < ROWS; ++r) acc[r] = 0.f;

#pragma unroll 2
  for (int d = 0; d < N_D; ++d) {
    const float* __restrict__ hrow = hT + (size_t)d * N_B + r0;  // uniform
    float wd = w[d];
#pragma unroll
    for (int r = 0; r < ROWS; ++r)
      acc[r] = fmaf(hrow[r], wd, acc[r]);      // SGPR-broadcast FMA
  }

  int c = cl[jc];
  if (valid) {
    int slot = c * REP + (lane & (REP - 1));   // ~1.6-way LDS contention
#pragma unroll
    for (int r = 0; r < ROWS; ++r)
      atomicAdd(&bkt[wave][r][slot], __expf(acc[r]));
  }
  __syncthreads();

  for (int i = t; i < ROWS * N_CLUSTERS; i += 256) {
    int r = i / N_CLUSTERS, cc = i % N_CLUSTERS;
    float v = 0.f;
#pragma unroll
    for (int wv = 0; wv < 4; ++wv)
#pragma unroll
      for (int p = 0; p < REP; ++p) v += bkt[wv][r][cc * REP + p];
    atomicAdd(&bucketg[(size_t)(r0 + r) * N_CLUSTERS + cc], v);
  }
}

// ---------------------------------------------------------------------------
// Kernel 4: out[b][c] = bucket[b][c] / (sum_c' bucket[b][c']) / max(cnt[c],1)
// ---------------------------------------------------------------------------
__global__ __launch_bounds__(256) void k4_fin(
    const float* __restrict__ bucketg, const float* __restrict__ cntg,
    float* __restrict__ out) {
  int idx = blockIdx.x * 256 + threadIdx.x;
  if (idx >= N_B * N_CLUSTERS) return;
  int row = idx / N_CLUSTERS, c = idx % N_CLUSTERS;
  const float* b = bucketg + (size_t)row * N_CLUSTERS;
  float total = 0.f;
#pragma unroll
  for (int k = 0; k < N_CLUSTERS; ++k) total += b[k];
  out[idx] = b[c] / (total * fmaxf(cntg[c], 1.f));
}

// ---------------------------------------------------------------------------
// Workspace layout (floats):
//   [0,    640)   S1
//   [640,  650)   counts
//   [1024, 11264) buckets (1024 x 10)
//   [12288,77824) hT (64 x 1024, transposed)
// Zero region: first 11264 floats.
// ---------------------------------------------------------------------------
extern "C" void kernel_launch(void* const* d_in, const int* in_sizes, int n_in,
                              void* d_out, int out_size, void* d_ws, size_t ws_size,
                              hipStream_t stream) {
  const float* input = (const float*)d_in[0];   // (1024, 10) f32
  const int* cl      = (const int*)d_in[1];     // (100000,) i32
  const float* W1    = (const float*)d_in[2];   // (100000, 64) f32
  const float* W2    = (const float*)d_in[3];   // (64, 100000) f32
  float* out = (float*)d_out;                   // (1024, 10) f32
  float* ws = (float*)d_ws;

  float* S1g     = ws;           // 640
  float* cntg    = ws + 640;     // 10
  float* bucketg = ws + 1024;    // 10240
  float* hT      = ws + 12288;   // 65536 (64 x 1024)

  hipMemsetAsync(d_ws, 0, (size_t)11264 * sizeof(float), stream);

  k1_segsum<<<512, 256, 0, stream>>>(cl, W1, S1g, cntg);
  k2_h<<<256, 256, 0, stream>>>(input, S1g, hT);

  // x = row-tile (fast) so consecutive blocks share the same 256-item W2
  // slice (64 KB) for L2 locality.
  dim3 g3(N_B / ROWS, (N_ITEMS + 255) / 256);  // (32, 391)
  k3_main<<<g3, 256, 0, stream>>>(W2, hT, cl, bucketg);

  k4_fin<<<(N_B * N_CLUSTERS + 255) / 256, 256, 0, stream>>>(bucketg, cntg, out);
}

// Round 4
// 674.113 us; speedup vs baseline: 1.3312x; 1.3312x over previous
//
#include <hip/hip_runtime.h>
#include <hip/hip_bf16.h>

#define N_B 1024
#define N_ITEMS 100000
#define N_CLUSTERS 10
#define N_D 64

// ---------------------------------------------------------------------------
// Kernel 1: S1[c][d] = sum_{i: cluster[i]==c} W1[i][d]; counts[c].
// Register accumulators per cluster (predicated selects), lane = d column,
// item index wave-uniform -> cl via scalar load, W1 row coalesced.
// ---------------------------------------------------------------------------
__global__ __launch_bounds__(256) void k1_segsum(
    const int* __restrict__ cl, const float* __restrict__ W1,
    float* __restrict__ S1g, float* __restrict__ cntg) {
  __shared__ float s1[4][N_CLUSTERS][N_D];   // 10 KB
  __shared__ float scnt[4][N_CLUSTERS];
  int t = threadIdx.x;
  int wave = t >> 6, lane = t & 63;

  float a[N_CLUSTERS];
  float cn[N_CLUSTERS];
#pragma unroll
  for (int k = 0; k < N_CLUSTERS; ++k) { a[k] = 0.f; cn[k] = 0.f; }

  int gw = blockIdx.x * 4 + wave;
  int nw = gridDim.x * 4;
#pragma unroll 4
  for (int i = gw; i < N_ITEMS; i += nw) {
    int c = cl[i];                              // wave-uniform -> s_load
    float w = W1[(size_t)i * N_D + lane];       // coalesced 256B/row
#pragma unroll
    for (int k = 0; k < N_CLUSTERS; ++k) {
      bool m = (c == k);
      a[k] += m ? w : 0.f;
      cn[k] += m ? 1.f : 0.f;
    }
  }

#pragma unroll
  for (int k = 0; k < N_CLUSTERS; ++k) s1[wave][k][lane] = a[k];
  if (lane == 0) {
#pragma unroll
    for (int k = 0; k < N_CLUSTERS; ++k) scnt[wave][k] = cn[k];
  }
  __syncthreads();

  const float* fs1 = (const float*)s1;
  for (int i = t; i < N_CLUSTERS * N_D; i += 256) {
    float v = fs1[i] + fs1[640 + i] + fs1[1280 + i] + fs1[1920 + i];
    atomicAdd(&S1g[i], v);
  }
  if (t < N_CLUSTERS) {
    float v = scnt[0][t] + scnt[1][t] + scnt[2][t] + scnt[3][t];
    atomicAdd(&cntg[t], v);
  }
}

// ---------------------------------------------------------------------------
// Kernel 2: hT[d][row] = sum_c input[row][c] * S1[c][d]   (64 x 1024,
// transposed so k3's per-d row-slice is contiguous -> s_load_dwordx16).
// ---------------------------------------------------------------------------
__global__ __launch_bounds__(256) void k2_h(
    const float* __restrict__ inp, const float* __restrict__ S1g,
    float* __restrict__ hT) {
  int idx = blockIdx.x * 256 + threadIdx.x;    // < 65536 exactly
  int d = idx >> 10, row = idx & 1023;
  float acc = 0.f;
#pragma unroll
  for (int c = 0; c < N_CLUSTERS; ++c)
    acc += inp[row * N_CLUSTERS + c] * S1g[c * N_D + d];  // S1 wave-uniform
  hT[idx] = acc;                               // coalesced
}

// ---------------------------------------------------------------------------
// Kernel 3 (hot): thread owns 1 item; acc[32] rows in VGPRs; W2 column read
// in chunks of 8 (w[8], CONSTANT-indexed inside fully-unrolled loops only —
// R3's scratch-spill came from `w[d]` with a partially-unrolled d loop).
// Per chunk: 8 independent coalesced global loads, then 8x32 FMAs whose h
// operand is a wave-uniform load (compiler promotes to s_load, proven by
// R3's SGPR=96). ~60 VGPR + 20 KB LDS -> ~8 blocks/CU, stalls hidden by TLP.
// ---------------------------------------------------------------------------
#define ROWS 32
#define DCHUNK 8
#define REP 4
__global__ __launch_bounds__(256) void k3_main(
    const float* __restrict__ W2, const float* __restrict__ hT,
    const int* __restrict__ cl, float* __restrict__ bucketg) {
  __shared__ float bkt[4][ROWS][N_CLUSTERS * REP];   // 20 KB
  int t = threadIdx.x;
  int wave = t >> 6, lane = t & 63;
  int r0 = blockIdx.x * ROWS;                  // 0..992
  int j = blockIdx.y * 256 + t;
  bool valid = (j < N_ITEMS);
  int jc = valid ? j : (N_ITEMS - 1);          // clamp: loads stay in-bounds

  float* fb = (float*)bkt;
  for (int i = t; i < 4 * ROWS * N_CLUSTERS * REP; i += 256) fb[i] = 0.f;
  __syncthreads();

  const float* __restrict__ w2col = W2 + jc;

  float acc[ROWS];
#pragma unroll
  for (int r = 0; r < ROWS; ++r) acc[r] = 0.f;

  for (int d0 = 0; d0 < N_D; d0 += DCHUNK) {   // dynamic outer loop
    float w[DCHUNK];
#pragma unroll
    for (int k = 0; k < DCHUNK; ++k)           // 8 independent coalesced loads
      w[k] = w2col[(size_t)(d0 + k) * N_ITEMS];
#pragma unroll
    for (int k = 0; k < DCHUNK; ++k) {
      const float* __restrict__ hrow = hT + (size_t)(d0 + k) * N_B + r0;
#pragma unroll
      for (int r = 0; r < ROWS; ++r)
        acc[r] = fmaf(hrow[r], w[k], acc[r]);  // s_load broadcast + v_fmac
    }
  }

  int c = cl[jc];
  if (valid) {
    int slot = c * REP + (lane & (REP - 1));   // ~1.6-way LDS contention
#pragma unroll
    for (int r = 0; r < ROWS; ++r)
      atomicAdd(&bkt[wave][r][slot], __expf(acc[r]));
  }
  __syncthreads();

  for (int i = t; i < ROWS * N_CLUSTERS; i += 256) {
    int r = i / N_CLUSTERS, cc = i % N_CLUSTERS;
    float v = 0.f;
#pragma unroll
    for (int wv = 0; wv < 4; ++wv)
#pragma unroll
      for (int p = 0; p < REP; ++p) v += bkt[wv][r][cc * REP + p];
    atomicAdd(&bucketg[(size_t)(r0 + r) * N_CLUSTERS + cc], v);
  }
}

// ---------------------------------------------------------------------------
// Kernel 4: out[b][c] = bucket[b][c] / (sum_c' bucket[b][c']) / max(cnt[c],1)
// ---------------------------------------------------------------------------
__global__ __launch_bounds__(256) void k4_fin(
    const float* __restrict__ bucketg, const float* __restrict__ cntg,
    float* __restrict__ out) {
  int idx = blockIdx.x * 256 + threadIdx.x;
  if (idx >= N_B * N_CLUSTERS) return;
  int row = idx / N_CLUSTERS, c = idx % N_CLUSTERS;
  const float* b = bucketg + (size_t)row * N_CLUSTERS;
  float total = 0.f;
#pragma unroll
  for (int k = 0; k < N_CLUSTERS; ++k) total += b[k];
  out[idx] = b[c] / (total * fmaxf(cntg[c], 1.f));
}

// ---------------------------------------------------------------------------
// Workspace layout (floats):
//   [0,    640)   S1
//   [640,  650)   counts
//   [1024, 11264) buckets (1024 x 10)
//   [12288,77824) hT (64 x 1024, transposed)
// Zero region: first 11264 floats.
// ---------------------------------------------------------------------------
extern "C" void kernel_launch(void* const* d_in, const int* in_sizes, int n_in,
                              void* d_out, int out_size, void* d_ws, size_t ws_size,
                              hipStream_t stream) {
  const float* input = (const float*)d_in[0];   // (1024, 10) f32
  const int* cl      = (const int*)d_in[1];     // (100000,) i32
  const float* W1    = (const float*)d_in[2];   // (100000, 64) f32
  const float* W2    = (const float*)d_in[3];   // (64, 100000) f32
  float* out = (float*)d_out;                   // (1024, 10) f32
  float* ws = (float*)d_ws;

  float* S1g     = ws;           // 640
  float* cntg    = ws + 640;     // 10
  float* bucketg = ws + 1024;    // 10240
  float* hT      = ws + 12288;   // 65536 (64 x 1024)

  hipMemsetAsync(d_ws, 0, (size_t)11264 * sizeof(float), stream);

  k1_segsum<<<512, 256, 0, stream>>>(cl, W1, S1g, cntg);
  k2_h<<<256, 256, 0, stream>>>(input, S1g, hT);

  // x = row-tile (fast) so consecutive blocks share the same 256-item W2
  // slice (64 KB) for L2 locality.
  dim3 g3(N_B / ROWS, (N_ITEMS + 255) / 256);  // (32, 391)
  k3_main<<<g3, 256, 0, stream>>>(W2, hT, cl, bucketg);

  k4_fin<<<(N_B * N_CLUSTERS + 255) / 256, 256, 0, stream>>>(bucketg, cntg, out);
}